// Round 6
// baseline (3321.710 us; speedup 1.0000x reference)
//
#include <hip/hip_runtime.h>
#include <hip/hip_bf16.h>

// Problem constants
#define Bn 256
#define Tn 336
#define KE 16

typedef __attribute__((ext_vector_type(8))) __bf16 bf16x8;
typedef __attribute__((ext_vector_type(4))) float f32x4;
typedef unsigned long long u64t;

#define MFMA(a, b, c) __builtin_amdgcn_mfma_f32_16x16x32_bf16((a), (b), (c), 0, 0, 0)

// ---------------- pack kernels (once per launch) ----------------

__global__ void pack_wh(const float* __restrict__ Wh, __bf16* __restrict__ hi,
                        __bf16* __restrict__ lo) {
    int i = blockIdx.x * 256 + threadIdx.x;  // 512*256
    int k = i >> 8, n = i & 255;
    float v = Wh[i];
    __bf16 h = (__bf16)v;
    hi[n * 512 + k] = h;
    lo[n * 512 + k] = (__bf16)(v - (float)h);
}

__global__ void pack_wx(const float* __restrict__ Wx, __bf16* __restrict__ out) {
    int i = blockIdx.x * 256 + threadIdx.x;  // 256*32
    int n = i >> 5, k = i & 31;
    out[i] = (__bf16)((k < 17) ? Wx[k * 256 + n] : 0.f);
}

__global__ void pack_split(const float* __restrict__ in, __bf16* __restrict__ hi,
                           __bf16* __restrict__ lo, int n) {
    int i = blockIdx.x * 256 + threadIdx.x;
    if (i >= n) return;
    float v = in[i];
    __bf16 h = (__bf16)v;
    hi[i] = h;
    lo[i] = (__bf16)(v - (float)h);
}

__global__ void pack_xin(const float* __restrict__ xl, const float* __restrict__ xe,
                         __bf16* __restrict__ out) {
    int i = blockIdx.x * 256 + threadIdx.x;  // 336*256*32
    int k = i & 31, b = (i >> 5) & 255, t = i >> 13;
    float v = 0.f;
    if (k == 0) v = xl[b * Tn + t];
    else if (k < 17) v = xe[(b * Tn + t) * KE + (k - 1)];
    out[i] = (__bf16)v;
}

// ---------------- MALL-coherent helpers (relaxed agent = sc1, no cache
// maintenance) ----------------

__device__ __forceinline__ bf16x8 ld16_mall(const __bf16* p) {
    union { u64t q[2]; bf16x8 v; } r;
    const u64t* q = (const u64t*)p;
    r.q[0] = __hip_atomic_load(q, __ATOMIC_RELAXED, __HIP_MEMORY_SCOPE_AGENT);
    r.q[1] = __hip_atomic_load(q + 1, __ATOMIC_RELAXED, __HIP_MEMORY_SCOPE_AGENT);
    return r.v;
}

__device__ __forceinline__ void st2_mall(__bf16* p, float f) {
    __bf16 h = (__bf16)f;
    union { __bf16 b; unsigned short u; } c; c.b = h;
    __hip_atomic_store((unsigned short*)p, c.u, __ATOMIC_RELAXED,
                       __HIP_MEMORY_SCOPE_AGENT);
}

// group barrier, RMW-free: each block stores VAL to its own flag dword
// (one 128B line per group); wave 0 polls the whole line, 1 load/lane.
// __syncthreads() drains vmcnt(0) before the flag store, so all prior sc1
// data stores are MALL-visible before the flag is.
#define GBAR(VAL)                                                              \
    do {                                                                       \
        __syncthreads();                                                       \
        if (tid == 0)                                                          \
            __hip_atomic_store(fl + l, (VAL), __ATOMIC_RELAXED,                \
                               __HIP_MEMORY_SCOPE_AGENT);                      \
        if (w == 0) {                                                          \
            const int* fp = fl + (lane & 31);                                  \
            for (;;) {                                                         \
                int v = __hip_atomic_load(fp, __ATOMIC_RELAXED,                \
                                          __HIP_MEMORY_SCOPE_AGENT);           \
                if (__all(v >= (VAL))) break;                                  \
                __builtin_amdgcn_s_sleep(1);                                   \
            }                                                                  \
        }                                                                      \
        __syncthreads();                                                       \
    } while (0)

// ---------------- persistent GRU kernel ----------------
// grid = 256 blocks, block = 512 threads (8 waves). group g = bid&7
// (32 blocks, batch rows [g*32, g*32+32)); block l = bid>>3 owns hidden
// units [16l,16l+16). Waves 0..5: (gate=w>>1, row-half=w&1) with W_hh
// fragments PINNED in registers (asm keep-alive); wave 6: x' tile with Wh
// fragments pinned; wave 7: staging/elementwise only.

__global__ __launch_bounds__(512, 2)
__attribute__((amdgpu_waves_per_eu(2, 2)))
void gru_persist(
    const __bf16* __restrict__ WhT_hi, const __bf16* __restrict__ WhT_lo,
    const __bf16* __restrict__ WxTP,
    const __bf16* __restrict__ Wih_hi, const __bf16* __restrict__ Wih_lo,
    const __bf16* __restrict__ Whh_hi, const __bf16* __restrict__ Whh_lo,
    const __bf16* __restrict__ XinP,
    const float* __restrict__ b_t, const float* __restrict__ b_ih,
    const float* __restrict__ b_hh,
    __bf16* xp, __bf16* hbf,  // shared via MALL-coherent ops
    int* cnt, float* __restrict__ out)
{
    __shared__ __align__(16) char lds[40960];
    // [0,32768):      hT  32 rows x 1024B (bf16 k=512), XOR-swizzled
    // [32768,40960):  ex  [2 half][4 plane][16 row][16 unit] f32

    const int bid = blockIdx.x;
    const int g = bid & 7, l = bid >> 3;
    const int tid = threadIdx.x;
    const int w = tid >> 6, lane = tid & 63;
    const int lr = lane & 15, ko = (lane >> 4) << 3;

    char* hT = lds;
    float* ex = (float*)(lds + 32768);

    __bf16* hbf_g = hbf + g * (32 * 512);
    __bf16* xp_g  = xp  + g * (32 * 256);
    int* fl = cnt + g * 32;  // 32 dwords = one 128B line per group

    const int mw = (w == 6) ? (l & 1) : (w & 1);  // row-half for this wave
    const int gg = (w < 6) ? (w >> 1) : 0;        // gate (waves 0..5)

    // ---- persistent phase-A weights in registers, asm-pinned ----
    const __bf16 *srcH, *srcL;
    if (w < 6) {
        size_t j = (size_t)(gg * 512 + l * 16 + lr) * 512 + ko;
        srcH = Whh_hi + j; srcL = Whh_lo + j;
    } else if (w == 6) {
        size_t j = (size_t)((l >> 1) * 16 + lr) * 512 + ko;
        srcH = WhT_hi + j; srcL = WhT_lo + j;
    } else {
        srcH = Whh_hi + ko; srcL = Whh_lo + ko;  // dummy (valid) for wave 7
    }
    f32x4 wHi[16], wLo[16];
#pragma unroll
    for (int k0 = 0; k0 < 16; ++k0) {
        wHi[k0] = *(const f32x4*)(srcH + k0 * 32);
        wLo[k0] = *(const f32x4*)(srcL + k0 * 32);
    }
#pragma unroll
    for (int k0 = 0; k0 < 16; ++k0) {
#pragma unroll
        for (int j = 0; j < 4; ++j) {
            float th = wHi[k0][j], tl = wLo[k0][j];
            asm volatile("" : "+v"(th));
            asm volatile("" : "+v"(tl));
            wHi[k0][j] = th; wLo[k0][j] = tl;
        }
    }
    bf16x8 wxf = {};
    float bt_r = 0.f;
    if (w == 6) {
        int c = (l >> 1) * 16 + lr;
        wxf = *(const bf16x8*)(WxTP + (size_t)c * 32 + ko);
        bt_r = b_t[c];
    }

    // phase-B W_ih row pointers (waves 0..5), cacheable L2-resident re-reads
    const __bf16* pBh = Wih_hi + (size_t)(gg * 512 + l * 16 + lr) * 256 + ko;
    const __bf16* pBl = Wih_lo + (size_t)(gg * 512 + l * 16 + lr) * 256 + ko;

    // elementwise per-thread state: (row = tid>>4, unit = tid&15)
    const int erow = tid >> 4, eunit = tid & 15;
    float bi0, bi1, bi2, bh0, bh1, bh2;
    {
        int u = l * 16 + eunit;
        bi0 = b_ih[u]; bi1 = b_ih[512 + u]; bi2 = b_ih[1024 + u];
        bh0 = b_hh[u]; bh1 = b_hh[512 + u]; bh2 = b_hh[1024 + u];
    }
    float hreg = 0.f;  // fp32 h carried in-register across all steps
    const int exi = (erow >> 4) * 1024 + (erow & 15) * 16 + eunit;

    const int arow = mw * 16 + lr;
    const int swz = (arow & 7) << 4;
    const int abaseH = arow * 1024 + (lane >> 4) * 16;

    for (int t = 0; t < Tn; ++t) {
        // ---- stage h -> hT (swizzled), MALL-coherent reads ----
#pragma unroll
        for (int e = 0; e < 4; ++e) {
            int r = e * 8 + w;
            bf16x8 v = ld16_mall(hbf_g + r * 512 + lane * 8);
            *(bf16x8*)(hT + ((r * 1024 + lane * 16) ^ ((r & 7) << 4))) = v;
        }
        __syncthreads();

        // ---- phase A: gh (waves 0-5) / x' (wave 6), K=512 hi/lo ----
        f32x4 accG = {};
        if (w < 7) {
            f32x4 aH = {}, aL = {};
#pragma unroll
            for (int k0 = 0; k0 < 16; ++k0) {
                bf16x8 a = *(const bf16x8*)(hT + ((abaseH + k0 * 64) ^ swz));
                aH = MFMA(a, __builtin_bit_cast(bf16x8, wHi[k0]), aH);
                aL = MFMA(a, __builtin_bit_cast(bf16x8, wLo[k0]), aL);
            }
            if (w == 6) {
                bf16x8 ax = *(const bf16x8*)(XinP +
                    ((size_t)t * 256 + g * 32 + mw * 16 + lr) * 32 + ko);
                aH = MFMA(ax, wxf, aH);
            }
            accG = aH + aL;
        }
        if (w == 6) {
            int c = (l >> 1) * 16 + lr;
#pragma unroll
            for (int r = 0; r < 4; ++r) {
                int row = mw * 16 + (lane >> 4) * 4 + r;
                float v = accG[r] + bt_r;
                float e2 = __expf(2.f * v);
                st2_mall(xp_g + row * 256 + c, 1.f - 2.f / (e2 + 1.f));
            }
        }

        GBAR(2 * t + 1);  // x' MALL-visible group-wide

        // ---- phase B: gx = x' @ W_ih.T (waves 0-5), K=256 hi/lo,
        //      A-fragments read DIRECTLY from MALL (no LDS staging) ----
        if (w < 6) {
            f32x4 xH = {}, xL = {};
            const __bf16* pA = xp_g + (size_t)(mw * 16 + lr) * 256 + ko;
#pragma unroll
            for (int k0 = 0; k0 < 8; ++k0) {
                bf16x8 a = ld16_mall(pA + k0 * 32);
                bf16x8 bh = *(const bf16x8*)(pBh + k0 * 32);
                bf16x8 bl = *(const bf16x8*)(pBl + k0 * 32);
                xH = MFMA(a, bh, xH);
                xL = MFMA(a, bl, xL);
            }
            f32x4 accX = xH + xL;
            float* exm = ex + mw * 1024;
            if (gg < 2) {
#pragma unroll
                for (int r = 0; r < 4; ++r)
                    exm[gg * 256 + ((lane >> 4) * 4 + r) * 16 + lr] =
                        accG[r] + accX[r];
            } else {
#pragma unroll
                for (int r = 0; r < 4; ++r) {
                    exm[2 * 256 + ((lane >> 4) * 4 + r) * 16 + lr] = accX[r];
                    exm[3 * 256 + ((lane >> 4) * 4 + r) * 16 + lr] = accG[r];
                }
            }
        }
        __syncthreads();

        // ---- elementwise GRU update (all 512 threads, 1 elem each) ----
        {
            float pr = ex[exi]       + bi0 + bh0;
            float pz = ex[exi + 256] + bi1 + bh1;
            float xn = ex[exi + 512] + bi2;
            float hn = ex[exi + 768] + bh2;
            float rr = 1.f / (1.f + __expf(-pr));
            float zz = 1.f / (1.f + __expf(-pz));
            float e2 = __expf(2.f * (xn + rr * hn));
            float nn = 1.f - 2.f / (e2 + 1.f);
            hreg = (1.f - zz) * nn + zz * hreg;
            st2_mall(hbf_g + erow * 512 + l * 16 + eunit, hreg);
            if (t == Tn - 1)
                out[(size_t)(g * 32 + erow) * 512 + l * 16 + eunit] = hreg;
        }

        if (t != Tn - 1) GBAR(2 * t + 2);  // h MALL-visible group-wide
    }
}

// ---------------- host launcher ----------------

extern "C" void kernel_launch(void* const* d_in, const int* in_sizes, int n_in,
                              void* d_out, int out_size, void* d_ws, size_t ws_size,
                              hipStream_t stream) {
    const float* x_l = (const float*)d_in[0];
    const float* x_e = (const float*)d_in[1];
    const float* Wh  = (const float*)d_in[2];
    const float* Wx  = (const float*)d_in[3];
    const float* bt  = (const float*)d_in[4];
    const float* Wih = (const float*)d_in[5];
    const float* Whh = (const float*)d_in[6];
    const float* bih = (const float*)d_in[7];
    const float* bhh = (const float*)d_in[8];

    char* ws = (char*)d_ws;
    __bf16* WhT_hi = (__bf16*)(ws + 0);          //  262144
    __bf16* WhT_lo = (__bf16*)(ws + 262144);     //  262144
    __bf16* WxTP   = (__bf16*)(ws + 524288);     //   16384
    __bf16* Wih_hi = (__bf16*)(ws + 540672);     //  786432
    __bf16* Wih_lo = (__bf16*)(ws + 1327104);    //  786432
    __bf16* Whh_hi = (__bf16*)(ws + 2113536);    // 1572864
    __bf16* Whh_lo = (__bf16*)(ws + 3686400);    // 1572864
    __bf16* XinP   = (__bf16*)(ws + 5259264);    // 5505024
    __bf16* xp     = (__bf16*)(ws + 10764288);   //  131072
    __bf16* hbf    = (__bf16*)(ws + 10895360);   //  262144
    int*    cnt    = (int*)   (ws + 11157504);   //    1024  -> total ~11.2 MB

    pack_wh<<<512, 256, 0, stream>>>(Wh, WhT_hi, WhT_lo);
    pack_wx<<<32, 256, 0, stream>>>(Wx, WxTP);
    pack_split<<<1536, 256, 0, stream>>>(Wih, Wih_hi, Wih_lo, 1536 * 256);
    pack_split<<<3072, 256, 0, stream>>>(Whh, Whh_hi, Whh_lo, 1536 * 512);
    pack_xin<<<10752, 256, 0, stream>>>(x_l, x_e, XinP);
    hipMemsetAsync(hbf, 0, 262144, stream);
    hipMemsetAsync(cnt, 0, 1024, stream);

    gru_persist<<<256, 512, 0, stream>>>(
        WhT_hi, WhT_lo, WxTP, Wih_hi, Wih_lo, Whh_hi, Whh_lo, XinP,
        bt, bih, bhh, xp, hbf, cnt, (float*)d_out);
}